// Round 3
// baseline (23.182 us; speedup 1.0000x reference)
//
#include <hip/hip_runtime.h>

// YOLO loss: B=32, A=5, C=80, gh=gw=52, HW=2704.
// d_in[0] net_out (B,A,85,HW) f32 | d_in[1] targets (B,A,6,HW) f32 (pre-masked)
// d_in[2] anchor_mask (B,A,HW) {0,1} | d_in[3] obj_mask (B,A,HW) {0,1}
// d_in[4] anchors (5,2) f32.  Output: scalar f32.

constexpr int B_  = 32;
constexpr int A_  = 5;
constexpr int C_  = 80;
constexpr int GW_ = 52;
constexpr int GH_ = 52;
constexpr int HW_ = GW_ * GH_;
constexpr int NCH = 5 + C_;           // 85
constexpr int TOTAL = B_ * A_ * HW_;  // 432640
constexpr int BLOCK = 256;
constexpr int CPT   = 2;              // cells per thread
constexpr int GRID  = TOTAL / (BLOCK * CPT);  // 845 exactly

constexpr float NET_W = 416.0f;
constexpr float NET_H = 416.0f;
constexpr float OBJ_THRESH  = 0.5f;
constexpr float COORD_SCALE = 5.0f;
constexpr float NOOBJ_SCALE = 1.0f;
constexpr float OBJ_SCALE   = 5.0f;
constexpr float CLASS_SCALE = 1.0f;

__device__ __forceinline__ float sigmoidf_(float x) {
    return 1.0f / (1.0f + __expf(-x));
}

// Per-cell box/coords/conf/IOU terms. Returns loss contribution; sets tc.
__device__ __forceinline__ float cell_terms(
    const float* __restrict__ net, const float* __restrict__ tgt,
    unsigned nbase, unsigned tbase, int hw, float aw, float ah,
    float cm, float om, float diff2, bool want_ce, int& tc)
{
    float loss = diff2 * (1.0f - om) * NOOBJ_SCALE;   // noobj1 (dense)

    const bool need_box = want_ce || (om != 0.0f);
    if (!need_box) return loss;

    const float p0 = net[nbase + 0u * HW_];
    const float p1 = net[nbase + 1u * HW_];
    const float p2 = net[nbase + 2u * HW_];
    const float p3 = net[nbase + 3u * HW_];
    const float t0 = tgt[tbase + 0u * HW_];
    const float t1 = tgt[tbase + 1u * HW_];
    const float t2 = tgt[tbase + 2u * HW_];
    const float t3 = tgt[tbase + 3u * HW_];

    const float sx = sigmoidf_(p0);
    const float sy = sigmoidf_(p1);

    if (want_ce) {
        const float dx = sx - t0;
        const float dy = sy - t1;
        const float pws = __expf(p2) * aw * (1.0f / NET_W);
        const float phs = __expf(p3) * ah * (1.0f / NET_H);
        const float tws = __expf(t2) * aw * (1.0f / NET_W);
        const float ths = __expf(t3) * ah * (1.0f / NET_H);
        const float dw = pws - tws;
        const float dh = phs - ths;
        loss += (dx * dx + dy * dy + dw * dw + dh * dh) * COORD_SCALE;
        loss += diff2 * OBJ_SCALE;
        tc = (int)tgt[tbase + 5u * HW_];
    } else {
        // no_resp: om==1, cm==0 -> IOU-gated noobj term
        const float col = (float)(hw % GW_);
        const float row = (float)(hw / GW_);

        const float pcx = (sx + col) * (NET_W / (float)GW_);
        const float pcy = (sy + row) * (NET_H / (float)GH_);
        const float pw  = __expf(p2) * aw;
        const float ph  = __expf(p3) * ah;
        const float px1 = pcx - 0.5f * pw;
        const float py1 = pcy - 0.5f * ph;
        const float px2 = px1 + pw;
        const float py2 = py1 + ph;

        const float gcx = (t0 + col) * (NET_W / (float)GW_);
        const float gcy = (t1 + row) * (NET_H / (float)GH_);
        const float gwd = __expf(t2) * aw;
        const float ghd = __expf(t3) * ah;
        const float gx1 = gcx - 0.5f * gwd;
        const float gy1 = gcy - 0.5f * ghd;
        const float gx2 = gx1 + gwd;
        const float gy2 = gy1 + ghd;

        const float iw = fmaxf(fminf(px2, gx2) - fmaxf(px1, gx1), 0.0f);
        const float ih = fmaxf(fminf(py2, gy2) - fmaxf(py1, gy1), 0.0f);
        const float inter  = iw * ih;
        const float area_p = (px2 - px1) * (py2 - py1);
        const float area_g = (gx2 - gx1) * (gy2 - gy1);
        const float iou = inter / (area_p + area_g - inter + 1e-9f);
        if (iou < OBJ_THRESH) loss += diff2 * NOOBJ_SCALE;
    }
    return loss;
}

__global__ __launch_bounds__(256) void yolo_loss_kernel(
    const float* __restrict__ net,     // (B*A*85*HW)
    const float* __restrict__ tgt,     // (B*A*6*HW)
    const float* __restrict__ amask,   // (B*A*HW)
    const float* __restrict__ omask,   // (B*A*HW)
    const float* __restrict__ anchors, // (5*2)
    float* __restrict__ out)
{
    const int t    = blockIdx.x * blockDim.x + threadIdx.x;
    const int lane = threadIdx.x & 63;

    const int cell0 = 2 * t;                 // even; cell0,cell0+1 share ba
    const int hw0   = cell0 % HW_;
    const int ba    = cell0 / HW_;
    const int a     = ba % A_;

    const unsigned nbase0 = (unsigned)ba * (unsigned)(NCH * HW_) + (unsigned)hw0;
    const unsigned tbase0 = (unsigned)ba * (unsigned)(6 * HW_)   + (unsigned)hw0;

    // dense vector loads (8B/lane, aligned: cell0/hw0 even)
    const float2 am2 = *reinterpret_cast<const float2*>(amask + cell0);
    const float2 om2 = *reinterpret_cast<const float2*>(omask + cell0);
    const float2 cf2 = *reinterpret_cast<const float2*>(net + nbase0 + 4u * HW_);

    const float aw = anchors[2 * a];
    const float ah = anchors[2 * a + 1];

    float loss = 0.0f;
    int   tc0 = 0, tc1 = 0;

    // slot 0
    const bool ce0 = (am2.x != 0.0f);
    {
        const float conf  = sigmoidf_(cf2.x);
        const float tcf   = ce0 ? tgt[tbase0 + 4u * HW_] : 0.0f;  // pre-masked
        const float d     = conf - tcf;
        const float diff2 = d * d;
        loss += cell_terms(net, tgt, nbase0, tbase0, hw0, aw, ah,
                           am2.x, om2.x, diff2, ce0, tc0);
        if (ce0) loss += 0.0f; // tc0 set inside
    }
    // slot 1
    const bool ce1 = (am2.y != 0.0f);
    {
        const float conf  = sigmoidf_(cf2.y);
        const float tcf   = ce1 ? tgt[tbase0 + 1u + 4u * HW_] : 0.0f;
        const float d     = conf - tcf;
        const float diff2 = d * d;
        loss += cell_terms(net, tgt, nbase0 + 1u, tbase0 + 1u, hw0 + 1, aw, ah,
                           am2.y, om2.y, diff2, ce1, tc1);
    }

    // ---- wave-cooperative class CE, 2 events per iteration for ILP ----
    {
        unsigned long long m0 = __ballot(ce0);
        unsigned long long m1 = __ballot(ce1);
        const int nb0i = (int)nbase0;
        while (m0 | m1) {
            int srcA, slotA;
            if (m0) { srcA = __ffsll((long long)m0) - 1; slotA = 0; m0 &= m0 - 1; }
            else    { srcA = __ffsll((long long)m1) - 1; slotA = 1; m1 &= m1 - 1; }
            const bool hasB = (m0 | m1) != 0ull;
            int srcB = 0, slotB = 0;
            if (hasB) {
                if (m0) { srcB = __ffsll((long long)m0) - 1; slotB = 0; m0 &= m0 - 1; }
                else    { srcB = __ffsll((long long)m1) - 1; slotB = 1; m1 &= m1 - 1; }
            }

            const unsigned nbA = (unsigned)__shfl(nb0i, srcA, 64) + (unsigned)slotA;
            const int      tcA = slotA ? __shfl(tc1, srcA, 64) : __shfl(tc0, srcA, 64);

            // issue all loads before any reduction (one HBM round trip for both events)
            const float xA0 = net[nbA + (unsigned)(5 + lane) * HW_];
            const float xA1 = (lane < 16) ? net[nbA + (unsigned)(69 + lane) * HW_] : -1e30f;

            float xB0 = 0.0f, xB1 = -1e30f;
            unsigned nbB = 0; int tcB = 0;
            if (hasB) {
                nbB = (unsigned)__shfl(nb0i, srcB, 64) + (unsigned)slotB;
                tcB = slotB ? __shfl(tc1, srcB, 64) : __shfl(tc0, srcB, 64);
                xB0 = net[nbB + (unsigned)(5 + lane) * HW_];
                xB1 = (lane < 16) ? net[nbB + (unsigned)(69 + lane) * HW_] : -1e30f;
            }

            // reduce event A
            {
                float mx = fmaxf(xA0, xA1);
                #pragma unroll
                for (int off = 32; off > 0; off >>= 1)
                    mx = fmaxf(mx, __shfl_xor(mx, off, 64));
                float s = __expf(xA0 - mx) + ((lane < 16) ? __expf(xA1 - mx) : 0.0f);
                #pragma unroll
                for (int off = 32; off > 0; off >>= 1)
                    s += __shfl_xor(s, off, 64);
                const int idx = (tcA < 64) ? tcA : (tcA - 64);
                const float xa = __shfl(xA0, idx, 64);
                const float xb = __shfl(xA1, idx, 64);
                const float xt = (tcA < 64) ? xa : xb;
                const float ce = -(xt - mx - __logf(s));
                if (lane == srcA) loss += ce * CLASS_SCALE;
            }
            // reduce event B
            if (hasB) {
                float mx = fmaxf(xB0, xB1);
                #pragma unroll
                for (int off = 32; off > 0; off >>= 1)
                    mx = fmaxf(mx, __shfl_xor(mx, off, 64));
                float s = __expf(xB0 - mx) + ((lane < 16) ? __expf(xB1 - mx) : 0.0f);
                #pragma unroll
                for (int off = 32; off > 0; off >>= 1)
                    s += __shfl_xor(s, off, 64);
                const int idx = (tcB < 64) ? tcB : (tcB - 64);
                const float xa = __shfl(xB0, idx, 64);
                const float xb = __shfl(xB1, idx, 64);
                const float xt = (tcB < 64) ? xa : xb;
                const float ce = -(xt - mx - __logf(s));
                if (lane == srcB) loss += ce * CLASS_SCALE;
            }
        }
    }

    // ---- block reduction -> one atomicAdd per block ----
    #pragma unroll
    for (int off = 32; off > 0; off >>= 1)
        loss += __shfl_down(loss, off, 64);

    __shared__ float wsum[4];
    const int wid = threadIdx.x >> 6;
    if (lane == 0) wsum[wid] = loss;
    __syncthreads();
    if (threadIdx.x == 0)
        atomicAdd(out, wsum[0] + wsum[1] + wsum[2] + wsum[3]);
}

extern "C" void kernel_launch(void* const* d_in, const int* in_sizes, int n_in,
                              void* d_out, int out_size, void* d_ws, size_t ws_size,
                              hipStream_t stream) {
    const float* net     = (const float*)d_in[0];
    const float* tgt     = (const float*)d_in[1];
    const float* amask   = (const float*)d_in[2];
    const float* omask   = (const float*)d_in[3];
    const float* anchors = (const float*)d_in[4];
    float* out = (float*)d_out;

    // atomics accumulate into out -> zero it each launch (graph-capture safe)
    hipMemsetAsync(out, 0, sizeof(float), stream);

    yolo_loss_kernel<<<GRID, BLOCK, 0, stream>>>(net, tgt, amask, omask, anchors, out);
}